// Round 10
// baseline (63.366 us; speedup 1.0000x reference)
//
#include <hip/hip_runtime.h>

#define NUM_CLASSES 100000
#define FEAT_DIM    256
#define BATCH       16384
#define ALPHA       0.5f
#define EPS_        1e-6f

typedef float f4 __attribute__((ext_vector_type(4)));
typedef f4 __attribute__((aligned(4))) f4_u;   // 4B-misaligned source reads

#define NQ (NUM_CLASSES * FEAT_DIM / 4)        // 6,400,000 output quads

// --- ws layout (bytes) ---
// Zeroed: counts + head + nslots
#define OFF_COUNTS    0u                        // 100000 * 4
#define OFF_HEAD      400000u                   // 100000 * 4 (sample_idx+1; 0 = empty)
#define OFF_NSLOTS    800000u                   // 4 (+12 pad)
#define OFF_ZERO_END  800016u
// Not zeroed (written before read every call):
#define OFF_TOUCHED   OFF_ZERO_END              // 16384 * 4 slot -> class row
#define OFF_NEXT      (OFF_TOUCHED + 65536u)    // 16384 * 4 chain links
#define OFF_PART2     (OFF_NEXT + 65536u)       // 16384 * 4 per-slot loss partials

__global__ void zero_kernel(f4* __restrict__ p, int n) {
    int i = blockIdx.x * blockDim.x + threadIdx.x;
    if (i < n) p[i] = (f4){0.f, 0.f, 0.f, 0.f};
}

// K1: histogram + compact touched-class list + per-class sample chains
__global__ void count_kernel(const int* __restrict__ target,
                             int* __restrict__ counts,
                             int* __restrict__ head,
                             int* __restrict__ next,
                             int* __restrict__ touched,
                             int* __restrict__ nslots) {
    int i = blockIdx.x * blockDim.x + threadIdx.x;
    if (i < BATCH) {
        int t = target[i];
        int old = atomicAdd(&counts[t], 1);
        if (old == 0) {
            int s = atomicAdd(nslots, 1);
            touched[s] = t;
        }
        int prev = atomicExch(&head[t], i + 1);
        next[i] = prev;
    }
}

// K2: PURE streaming copy — zero branches, zero scalar loads. This dispatch's
// hbm_gbps is the platform's true rate for this buffer pair (diagnostic per
// rule "bench a known-good kernel before calling a ceiling").
// out[4q..4q+3] = centers[4q-1..4q+2] for q in [1, NQ). Quad 0 and the last
// element are handled in reduce_fin; touched rows are overwritten by K3.
__global__ __launch_bounds__(256) void copy_kernel(const float* __restrict__ centers,
                                                   float* __restrict__ out) {
    const int stride = gridDim.x * blockDim.x;          // 3,276,800
    for (int q = 1 + blockIdx.x * blockDim.x + threadIdx.x; q < NQ; q += stride) {
        const f4 v = *(const f4_u*)(centers + 4 * (size_t)q - 1);
        __builtin_nontemporal_store(v, (f4*)(out + 4 * (size_t)q));
    }
}

// K3: wave per TOUCHED class (~15.2K waves). Chain-walk features, recompute
// the row, overwrite the copied values, emit complete per-class loss partial.
__global__ __launch_bounds__(256) void fix_kernel(
                               const float* __restrict__ centers,
                               const float* __restrict__ features,
                               const int*   __restrict__ counts,
                               const int*   __restrict__ head,
                               const int*   __restrict__ next,
                               const int*   __restrict__ touched,
                               const int*   __restrict__ nslots,
                               float*       __restrict__ out_centers,  // d_out + 1
                               float*       __restrict__ partials2) {
    const int lane = threadIdx.x & 63;
    const int slot = blockIdx.x * 4 + (threadIdx.x >> 6);
    if (slot >= *nslots) return;
    const int row = touched[slot];

    const size_t base = (size_t)row * FEAT_DIM + lane;
    const float* crow = centers + base;
    float*       orow = out_centers + base;
    const float c0 = crow[0], c1 = crow[64], c2 = crow[128], c3 = crow[192];
    const int cnt = counts[row];                  // wave-uniform, >= 1

    float s0 = 0.f, s1 = 0.f, s2 = 0.f, s3 = 0.f, sq = 0.f;
    for (int j = head[row]; j != 0; j = next[j - 1]) {   // avg ~1.1 iters
        const float* frow = features + (size_t)(j - 1) * FEAT_DIM + lane;
        const float f0 = frow[0], f1 = frow[64], f2 = frow[128], f3 = frow[192];
        s0 += f0; s1 += f1; s2 += f2; s3 += f3;
        sq += f0*f0 + f1*f1 + f2*f2 + f3*f3;
    }

    const float fc  = (float)cnt;
    const float inv = ALPHA / (fc + EPS_);
    orow[0]   = c0 - inv * (fc * c0 - s0);
    orow[64]  = c1 - inv * (fc * c1 - s1);
    orow[128] = c2 - inv * (fc * c2 - s2);
    orow[192] = c3 - inv * (fc * c3 - s3);

    float red = sq
              + fc * (c0*c0 + c1*c1 + c2*c2 + c3*c3)
              - 2.0f * (c0*s0 + c1*s1 + c2*s2 + c3*s3);
    #pragma unroll
    for (int off = 32; off > 0; off >>= 1)
        red += __shfl_down(red, off, 64);
    if (lane == 0) partials2[slot] = red;
}

// K4: single-block reduce over ns partials + boundary elements skipped by copy.
__global__ void reduce_fin(const float* __restrict__ partials2,
                           const int*   __restrict__ nslots,
                           const int*   __restrict__ counts,
                           const float* __restrict__ centers,
                           float* __restrict__ out) {
    const int ns = *nslots;
    float s = 0.0f;
    for (int i = threadIdx.x; i < ns; i += 1024) s += partials2[i];
    #pragma unroll
    for (int off = 32; off > 0; off >>= 1)
        s += __shfl_down(s, off, 64);
    __shared__ float wsum[16];
    const int lane = threadIdx.x & 63;
    const int wid  = threadIdx.x >> 6;
    if (lane == 0) wsum[wid] = s;
    __syncthreads();
    if (threadIdx.x == 0) {
        float tot = 0.0f;
        #pragma unroll
        for (int k = 0; k < 16; ++k) tot += wsum[k];
        out[0] = tot * (1.0f / ((float)BATCH * (float)FEAT_DIM));
        // boundary elements not covered by copy_kernel's quads:
        // out[1..3] (row 0 cols 0-2) and out[NQ*4] (last row col 255) — only
        // when untouched (fix_kernel already wrote them for touched rows).
        if (counts[0] == 0) {
            out[1] = centers[0]; out[2] = centers[1]; out[3] = centers[2];
        }
        if (counts[NUM_CLASSES - 1] == 0) {
            out[(size_t)NQ * 4] = centers[(size_t)NQ * 4 - 1];
        }
    }
}

extern "C" void kernel_launch(void* const* d_in, const int* in_sizes, int n_in,
                              void* d_out, int out_size, void* d_ws, size_t ws_size,
                              hipStream_t stream) {
    const float* centers  = (const float*)d_in[0];
    const float* features = (const float*)d_in[1];
    const int*   target   = (const int*)d_in[2];

    float* out         = (float*)d_out;
    float* out_centers = out + 1;

    char* ws = (char*)d_ws;
    int*   counts    = (int*)(ws + OFF_COUNTS);
    int*   head      = (int*)(ws + OFF_HEAD);
    int*   nslots    = (int*)(ws + OFF_NSLOTS);
    int*   touched   = (int*)(ws + OFF_TOUCHED);
    int*   next      = (int*)(ws + OFF_NEXT);
    float* partials2 = (float*)(ws + OFF_PART2);

    const int nzero = (int)(OFF_ZERO_END / 16u);
    zero_kernel<<<(nzero + 255) / 256, 256, 0, stream>>>((f4*)ws, nzero);

    count_kernel<<<(BATCH + 255) / 256, 256, 0, stream>>>(target, counts, head, next,
                                                          touched, nslots);

    copy_kernel<<<12800, 256, 0, stream>>>(centers, out);

    fix_kernel<<<BATCH / 4, 256, 0, stream>>>(centers, features, counts, head, next,
                                              touched, nslots, out_centers, partials2);

    reduce_fin<<<1, 1024, 0, stream>>>(partials2, nslots, counts, centers, out);
}

// Round 11
// 53.474 us; speedup vs baseline: 1.1850x; 1.1850x over previous
//
#include <hip/hip_runtime.h>

#define NUM_CLASSES 100000
#define FEAT_DIM    256
#define BATCH       16384
#define ALPHA       0.5f
#define EPS_        1e-6f

typedef float f4 __attribute__((ext_vector_type(4)));

// --- ws layout (bytes) ---
// Zeroed: counts + head + partw + done (contiguous)
#define OFF_COUNTS    0u                          // 100000 * 4
#define OFF_HEAD      400000u                     // 100000 * 4 (sample_idx+1; 0 = empty)
#define OFF_PARTW     800000u                     // 100000 * 4 per-row loss partials
#define OFF_DONE      1200000u                    // 4 (+12 pad)
#define OFF_ZERO_END  1200016u                    // divisible by 16
// Not zeroed (written before read every call):
#define OFF_NEXT      OFF_ZERO_END                // 16384 * 4 chain links
#define OFF_PART64    (OFF_NEXT + 65536u)         // 64 * 4 stage-1 partials

// K0: custom zero (hipMemsetAsync's fillBuffer costs ~60us fixed in-graph)
__global__ void zero_kernel(f4* __restrict__ p, int n) {
    int i = blockIdx.x * blockDim.x + threadIdx.x;
    if (i < n) p[i] = (f4){0.f, 0.f, 0.f, 0.f};
}

// K1: histogram + per-class linked chain of samples (int atomics only)
__global__ void count_kernel(const int* __restrict__ target,
                             int* __restrict__ counts,
                             int* __restrict__ head,
                             int* __restrict__ next) {
    int i = blockIdx.x * blockDim.x + threadIdx.x;
    if (i < BATCH) {
        int t = target[i];
        atomicAdd(&counts[t], 1);
        int prev = atomicExch(&head[t], i + 1);
        next[i] = prev;
    }
}

// K2: wave per class row, lane l owns cols {l, l+64, l+128, l+192} — every
// load/store instruction is 256B contiguous across the wave, 4B-aligned on
// both source and destination. Runs at the measured platform rate for the
// +4B-shifted read->write stream pair (~4.7 TB/s L2-level; branch-free pure
// copy measured identical in R10). Store pattern / alignment / nt-policy /
// wave-shape variants all tested null or negative (R6-R10).
__global__ __launch_bounds__(256) void rewrite_kernel(
                               const float* __restrict__ centers,
                               const float* __restrict__ features,
                               const int*   __restrict__ counts,
                               const int*   __restrict__ head,
                               const int*   __restrict__ next,
                               float*       __restrict__ out_centers,  // d_out + 1
                               float*       __restrict__ partw) {      // [NUM_CLASSES], pre-zeroed
    const int lane = threadIdx.x & 63;
    const int row  = blockIdx.x * 4 + (threadIdx.x >> 6);   // grid covers classes exactly

    const size_t base = (size_t)row * FEAT_DIM + lane;
    const float* crow = centers + base;
    float*       orow = out_centers + base;

    const float c0 = crow[0], c1 = crow[64], c2 = crow[128], c3 = crow[192];
    const int cnt = counts[row];                  // wave-uniform

    if (cnt == 0) {                               // ~85% of rows: pure streaming copy
        __builtin_nontemporal_store(c0, orow);
        __builtin_nontemporal_store(c1, orow + 64);
        __builtin_nontemporal_store(c2, orow + 128);
        __builtin_nontemporal_store(c3, orow + 192);
        return;
    }

    float s0 = 0.f, s1 = 0.f, s2 = 0.f, s3 = 0.f, sq = 0.f;
    for (int j = head[row]; j != 0; j = next[j - 1]) {   // avg 1.1 iters, max ~8
        const float* frow = features + (size_t)(j - 1) * FEAT_DIM + lane;
        const float f0 = frow[0], f1 = frow[64], f2 = frow[128], f3 = frow[192];
        s0 += f0; s1 += f1; s2 += f2; s3 += f3;
        sq += f0*f0 + f1*f1 + f2*f2 + f3*f3;
    }

    const float fc  = (float)cnt;
    const float inv = ALPHA / (fc + EPS_);
    __builtin_nontemporal_store(c0 - inv * (fc * c0 - s0), orow);
    __builtin_nontemporal_store(c1 - inv * (fc * c1 - s1), orow + 64);
    __builtin_nontemporal_store(c2 - inv * (fc * c2 - s2), orow + 128);
    __builtin_nontemporal_store(c3 - inv * (fc * c3 - s3), orow + 192);

    // complete loss partial: sum||f||^2 + cnt*||c||^2 - 2*c.sum_f
    float red = sq
              + fc * (c0*c0 + c1*c1 + c2*c2 + c3*c3)
              - 2.0f * (c0*s0 + c1*s1 + c2*s2 + c3*s3);
    #pragma unroll
    for (int off = 32; off > 0; off >>= 1)
        red += __shfl_down(red, off, 64);
    if (lane == 0) partw[row] = red;              // plain store (partw pre-zeroed)
}

// K3: 2-stage reduce fused via last-block-done. Deterministic: fixed-order
// final sum over 64 partials by the unique last block.
__global__ void reduce_fin(const float* __restrict__ partw,
                           float* __restrict__ part64,
                           int*   __restrict__ done,
                           float* __restrict__ out) {
    float s = 0.f;
    for (int i = blockIdx.x * 256 + threadIdx.x; i < NUM_CLASSES; i += 64 * 256)
        s += partw[i];
    #pragma unroll
    for (int off = 32; off > 0; off >>= 1)
        s += __shfl_down(s, off, 64);
    __shared__ float wsum[4];
    const int lane = threadIdx.x & 63;
    const int wid  = threadIdx.x >> 6;
    if (lane == 0) wsum[wid] = s;
    __syncthreads();
    if (threadIdx.x == 0) {
        part64[blockIdx.x] = wsum[0] + wsum[1] + wsum[2] + wsum[3];
        __threadfence();                                   // publish before counting
        int old = atomicAdd(done, 1);                      // device-scope
        if (old == 63) {                                   // unique last block
            __threadfence();                               // acquire all part64 stores
            float acc = 0.f;
            #pragma unroll
            for (int k = 0; k < 64; ++k) acc += part64[k];
            out[0] = acc * (1.0f / ((float)BATCH * (float)FEAT_DIM));
        }
    }
}

extern "C" void kernel_launch(void* const* d_in, const int* in_sizes, int n_in,
                              void* d_out, int out_size, void* d_ws, size_t ws_size,
                              hipStream_t stream) {
    const float* centers  = (const float*)d_in[0];
    const float* features = (const float*)d_in[1];
    const int*   target   = (const int*)d_in[2];

    float* out         = (float*)d_out;
    float* out_centers = out + 1;

    char* ws = (char*)d_ws;
    int*   counts  = (int*)(ws + OFF_COUNTS);
    int*   head    = (int*)(ws + OFF_HEAD);
    float* partw   = (float*)(ws + OFF_PARTW);
    int*   done    = (int*)(ws + OFF_DONE);
    int*   next    = (int*)(ws + OFF_NEXT);
    float* part64  = (float*)(ws + OFF_PART64);

    const int nzero = (int)(OFF_ZERO_END / 16u);   // counts + head + partw + done
    zero_kernel<<<(nzero + 255) / 256, 256, 0, stream>>>((f4*)ws, nzero);

    count_kernel<<<(BATCH + 255) / 256, 256, 0, stream>>>(target, counts, head, next);

    rewrite_kernel<<<NUM_CLASSES / 4, 256, 0, stream>>>(centers, features, counts, head,
                                                        next, out_centers, partw);

    reduce_fin<<<64, 256, 0, stream>>>(partw, part64, done, out);
}